// Round 2
// 435.261 us; speedup vs baseline: 1.0050x; 1.0050x over previous
//
#include <hip/hip_runtime.h>
#include <cmath>

typedef __bf16 bf16;
typedef __bf16 bf16x8 __attribute__((ext_vector_type(8)));
typedef __bf16 bf16x4 __attribute__((ext_vector_type(4)));
typedef __bf16 bf16x2 __attribute__((ext_vector_type(2)));
typedef float f32x4 __attribute__((ext_vector_type(4)));
typedef int i32x4 __attribute__((ext_vector_type(4)));

#define S_LEN 2048
#define QK_LD 3072       // NHEADS * 192

__device__ __forceinline__ void async_copy16(const bf16* g, bf16* l) {
    __builtin_amdgcn_global_load_lds(
        (const __attribute__((address_space(1))) void*)g,
        (__attribute__((address_space(3))) void*)l, 16, 0, 0);
}

__device__ __forceinline__ unsigned packbf(float a, float b) {
    bf16x2 v; v[0] = (bf16)a; v[1] = (bf16)b;
    return __builtin_bit_cast(unsigned, v);
}

// ---------------- cast x (fp32) -> bf16 ----------------
__global__ __launch_bounds__(256) void cast_f32_bf16(const float* __restrict__ in,
                                                     bf16* __restrict__ out) {
    size_t i = ((size_t)blockIdx.x * 256 + threadIdx.x) * 8;
    float4 a = *(const float4*)(in + i);
    float4 b = *(const float4*)(in + i + 4);
    bf16x8 v;
    v[0] = (bf16)a.x; v[1] = (bf16)a.y; v[2] = (bf16)a.z; v[3] = (bf16)a.w;
    v[4] = (bf16)b.x; v[5] = (bf16)b.y; v[6] = (bf16)b.z; v[7] = (bf16)b.w;
    *(bf16x8*)(out + i) = v;
}

// ---------------- fused transpose-cast of all 7 weights, one dispatch ----------------
struct TSeg { const float* src; bf16* dst; int K, N, blk0; };
struct TArgs { TSeg s[7]; };

__global__ __launch_bounds__(256) void transpose_all(TArgs a) {
    __shared__ float tile[64][68];
    int b = blockIdx.x, si = 0;
#pragma unroll
    for (int i = 1; i < 7; ++i) if (b >= a.s[i].blk0) si = i;
    TSeg sg = a.s[si];
    int local = b - sg.blk0;
    int kTiles = sg.K >> 6;
    int kt = local % kTiles, nt = local / kTiles;
    int k0 = kt * 64, n0 = nt * 64;
    int K = sg.K, N = sg.N;
    int t = threadIdx.x;
#pragma unroll
    for (int i = 0; i < 4; ++i) {
        int c = t + i * 256;
        int r = c >> 4, off = (c & 15) * 4;
        float4 v = *(const float4*)(sg.src + (size_t)(k0 + r) * N + n0 + off);
        tile[r][off] = v.x; tile[r][off + 1] = v.y;
        tile[r][off + 2] = v.z; tile[r][off + 3] = v.w;
    }
    __syncthreads();
#pragma unroll
    for (int i = 0; i < 2; ++i) {
        int c = t + i * 256;
        int nr = c >> 3, koff = (c & 7) * 8;
        bf16x8 v;
#pragma unroll
        for (int j = 0; j < 8; ++j) v[j] = (bf16)tile[koff + j][nr];
        *(bf16x8*)(sg.dst + (size_t)(n0 + nr) * K + k0 + koff) = v;
    }
}

// ---------------- bias concat + rope table, one dispatch ----------------
__global__ __launch_bounds__(256) void setup_small(const float* __restrict__ bd,
                                                   const float* __restrict__ bqd,
                                                   const float* __restrict__ bkr,
                                                   const float* __restrict__ bqu,
                                                   const float* __restrict__ bqr,
                                                   float* __restrict__ bcat,
                                                   float2* __restrict__ tab) {
    if (blockIdx.x < 21) {
        int i = blockIdx.x * 256 + threadIdx.x;
        if (i < 512) bcat[i] = bd[i];
        else if (i < 1280) bcat[i] = bqd[i - 512];
        else if (i < 2304) bcat[i] = bkr[i - 1280];
        else if (i < 4352) bcat[i] = bqu[i - 2304];
        else if (i < 5376) bcat[i] = bqr[i - 4352];
    } else {
        int id = (blockIdx.x - 21) * 256 + threadIdx.x;   // 65536
        int s = id >> 5, i = id & 31;
        float f = expf(-0.2878231366242557f * (float)i);  // ln(10000)/32
        float ang = (float)s * f;
        tab[id] = make_float2(cosf(ang), sinf(ang));
    }
}

// ---------------- m97-style bf16 GEMM core with fused epilogues ----------------
// mode 1: fp32 out0, stride Ndim
// mode 4: col<1280 -> bf16 out0 (xproj, stride 2304); col>=1280 -> rope -> out1 (kbuf)
// mode 5: col<2048 -> head-scatter out0 (qbuf); col>=2048 -> rope -> out0 (qbuf)
// mode 6: head-scatter out0 (kbuf) + transposed pack out1 (vt[bh][d][s])
__device__ __forceinline__ void gemm_core(const bf16* __restrict__ A, int lda,
                                          const bf16* __restrict__ Bt,
                                          const float* __restrict__ bias,
                                          void* __restrict__ out0,
                                          void* __restrict__ out1,
                                          int Ndim, int Kdim, int mode,
                                          const float2* __restrict__ tab,
                                          int bn, int bm, bf16* As, bf16* Bs) {
    int t = threadIdx.x;
    int w = t >> 6, lane = t & 63;
    int wm = (w >> 1) * 64, wn = (w & 1) * 64;
    int l15 = lane & 15, q4 = lane >> 4;
    f32x4 acc[4][4] = {};

    int lrow = lane >> 2;
    int lcol = (lane & 3) * 8;
    int c0 = w * 2, c1 = w * 2 + 1;
    const bf16* aS0 = A  + (size_t)(bm * 128 + c0 * 16 + lrow) * lda + lcol;
    const bf16* aS1 = A  + (size_t)(bm * 128 + c1 * 16 + lrow) * lda + lcol;
    const bf16* bS0 = Bt + (size_t)(bn * 128 + c0 * 16 + lrow) * Kdim + lcol;
    const bf16* bS1 = Bt + (size_t)(bn * 128 + c1 * 16 + lrow) * Kdim + lcol;
    bf16* aD0 = &As[c0 * 512]; bf16* aD1 = &As[c1 * 512];
    bf16* bD0 = &Bs[c0 * 512]; bf16* bD1 = &Bs[c1 * 512];

    for (int kt = 0; kt < Kdim; kt += 32) {
        async_copy16(aS0 + kt, aD0);
        async_copy16(aS1 + kt, aD1);
        async_copy16(bS0 + kt, bD0);
        async_copy16(bS1 + kt, bD1);
        __syncthreads();
        bf16x8 af[4], bfr[4];
#pragma unroll
        for (int mb = 0; mb < 4; ++mb)
            af[mb] = *(const bf16x8*)&As[(wm + mb * 16 + l15) * 32 + q4 * 8];
#pragma unroll
        for (int nb = 0; nb < 4; ++nb)
            bfr[nb] = *(const bf16x8*)&Bs[(wn + nb * 16 + l15) * 32 + q4 * 8];
#pragma unroll
        for (int mb = 0; mb < 4; ++mb)
#pragma unroll
            for (int nb = 0; nb < 4; ++nb)
                acc[mb][nb] = __builtin_amdgcn_mfma_f32_16x16x32_bf16(
                    af[mb], bfr[nb], acc[mb][nb], 0, 0, 0);
        __syncthreads();
    }

#pragma unroll
    for (int mb = 0; mb < 4; ++mb) {
        int row = bm * 128 + wm + mb * 16 + q4 * 4;
#pragma unroll
        for (int nb = 0; nb < 4; ++nb) {
            int col = bn * 128 + wn + nb * 16 + l15;
            float bv = bias[col];
            if (mode == 1) {
#pragma unroll
                for (int r = 0; r < 4; ++r)
                    ((float*)out0)[(size_t)(row + r) * Ndim + col] = acc[mb][nb][r] + bv;
            } else if (mode == 4) {
                if (col < 1280) {
#pragma unroll
                    for (int r = 0; r < 4; ++r)
                        ((bf16*)out0)[(size_t)(row + r) * 2304 + col] =
                            (bf16)(acc[mb][nb][r] + bv);
                } else {
                    int rel = col - 1280;
                    int hh = rel >> 6, idx = rel & 63, ii = idx >> 1, odd = idx & 1;
#pragma unroll
                    for (int r = 0; r < 4; ++r) {
                        float vv = acc[mb][nb][r] + bv;
                        float pp = __shfl_xor(vv, 1, 64);
                        float2 cs = tab[((row + r) & 2047) * 32 + ii];
                        float o = vv * cs.x + (odd ? pp * cs.y : -pp * cs.y);
                        ((bf16*)out1)[(size_t)(row + r) * QK_LD + hh * 192 + 128 + idx] =
                            (bf16)o;
                    }
                }
            } else if (mode == 5) {
                if (col < 2048) {
                    int hh = col >> 7, dd = col & 127;
#pragma unroll
                    for (int r = 0; r < 4; ++r)
                        ((bf16*)out0)[(size_t)(row + r) * QK_LD + hh * 192 + dd] =
                            (bf16)(acc[mb][nb][r] + bv);
                } else {
                    int rel = col - 2048;
                    int hh = rel >> 6, idx = rel & 63, ii = idx >> 1, odd = idx & 1;
#pragma unroll
                    for (int r = 0; r < 4; ++r) {
                        float vv = acc[mb][nb][r] + bv;
                        float pp = __shfl_xor(vv, 1, 64);
                        float2 cs = tab[((row + r) & 2047) * 32 + ii];
                        float o = vv * cs.x + (odd ? pp * cs.y : -pp * cs.y);
                        ((bf16*)out0)[(size_t)(row + r) * QK_LD + hh * 192 + 128 + idx] =
                            (bf16)o;
                    }
                }
            } else {   // mode 6: kv_up -> kbuf scatter + vt transpose-pack
                int hh = col >> 7, dd = col & 127;
                bf16x4 pack;
#pragma unroll
                for (int r = 0; r < 4; ++r) {
                    float vv = acc[mb][nb][r] + bv;
                    ((bf16*)out0)[(size_t)(row + r) * QK_LD + hh * 192 + dd] = (bf16)vv;
                    pack[r] = (bf16)vv;
                }
                int bidx = row >> 11, srow = row & 2047;
                *(bf16x4*)((bf16*)out1 +
                           ((size_t)(bidx * 16 + hh) * 128 + dd) * S_LEN + srow) = pack;
            }
        }
    }
}

__global__ __launch_bounds__(256) void gemm_bt(const bf16* __restrict__ A, int lda,
                                               const bf16* __restrict__ Bt,
                                               const float* __restrict__ bias,
                                               void* __restrict__ out0,
                                               void* __restrict__ out1,
                                               int Ndim, int Kdim, int mode,
                                               const float2* __restrict__ tab) {
    __shared__ bf16 As[128 * 32];
    __shared__ bf16 Bs[128 * 32];
    gemm_core(A, lda, Bt, bias, out0, out1, Ndim, Kdim, mode, tab,
              blockIdx.x, blockIdx.y, As, Bs);
}

// fused up-projection GEMMs: bn<16 -> kv_up (mode 6, K=512); bn>=16 -> q_up (mode 5, K=768)
__global__ __launch_bounds__(256) void gemm_up(const bf16* __restrict__ xproj,
                                               const bf16* __restrict__ WuT,
                                               const float* __restrict__ bu,
                                               void* __restrict__ kbuf,
                                               void* __restrict__ vt,
                                               const bf16* __restrict__ W2T,
                                               const float* __restrict__ bq,
                                               void* __restrict__ qbuf,
                                               const float2* __restrict__ tab) {
    __shared__ bf16 As[128 * 32];
    __shared__ bf16 Bs[128 * 32];
    int bn = blockIdx.x;
    if (bn < 16)
        gemm_core(xproj, 2304, WuT, bu, kbuf, vt, 2048, 512, 6, tab,
                  bn, blockIdx.y, As, Bs);
    else
        gemm_core(xproj + 512, 2304, W2T, bq, qbuf, nullptr, 3072, 768, 5, tab,
                  bn - 16, blockIdx.y, As, Bs);
}

// ---------------- attention v5 ----------------
// KVBLK=32, double-buffered K/V in LDS (one barrier per tile), XOR-swizzled
// layouts (conflict-free), P kept entirely in registers via shfl redistribution,
// s_setprio around MFMA clusters. Grid (x=bh, y=qt) keeps XCD L2 affinity.
__global__ __launch_bounds__(256, 2) void attn(const bf16* __restrict__ qbuf,
                                               const bf16* __restrict__ kbuf,
                                               const bf16* __restrict__ vt,
                                               bf16* __restrict__ attnout) {
    __shared__ bf16 Ks[2][32 * 192];    // 32 keys x 192, 16B units XOR (row&7)
    __shared__ bf16 Vs[2][128 * 32];    // 128 d x 32 keys, 16B units XOR (row&3)
    int bh = blockIdx.x;                // 0..31
    int qt = blockIdx.y;                // 0..15
    int b = bh >> 4, h = bh & 15;
    int t = threadIdx.x, w = t >> 6, lane = t & 63;
    int l15 = lane & 15, q4 = lane >> 4;
    const float scale = 0.08838834764831845f;

    // Q: 32 rows x 192 per wave, register-resident (B-operand)
    bf16x8 qf[2][6];
    {
        size_t base = (size_t)(b * S_LEN + qt * 128 + w * 32) * QK_LD + h * 192;
#pragma unroll
        for (int mb = 0; mb < 2; ++mb)
#pragma unroll
            for (int c = 0; c < 6; ++c)
                qf[mb][c] = *(const bf16x8*)(qbuf + base +
                            (size_t)(mb * 16 + l15) * QK_LD + c * 32 + q4 * 8);
    }

    f32x4 oacc[2][8] = {};
    float denom[2] = {0.f, 0.f};
    const bf16* kb_base = kbuf + (size_t)b * S_LEN * QK_LD + h * 192;
    const bf16* vt_base = vt + (size_t)bh * 128 * S_LEN;

    // staging indices: K tile = 32 rows x 192 (768 x 16B), V tile = 128 x 32 (512 x 16B)
    int kg_[3], kl_[3], vg_[2], vl_[2];
#pragma unroll
    for (int i = 0; i < 3; ++i) {
        int c = t + (i << 8);                 // 0..767
        int kr = c / 24, u = c % 24;
        kg_[i] = kr * QK_LD + u * 8;
        kl_[i] = kr * 192 + ((u ^ (kr & 7)) << 3);
    }
#pragma unroll
    for (int i = 0; i < 2; ++i) {
        int c = t + (i << 8);                 // 0..511
        int vd = c >> 2, u = c & 3;
        vg_[i] = vd * S_LEN + u * 8;
        vl_[i] = vd * 32 + ((u ^ (vd & 3)) << 3);
    }

    // shfl source lanes for in-register P redistribution
    int srcA = ((lane & 16) << 1) + l15;      // ((q4&1)*2 + 0)*16 + l15
    int srcB = srcA + 16;                     // ((q4&1)*2 + 1)*16 + l15
    bool hiK = lane >= 32;                    // q4 >= 2  -> source nk block 1

    // prologue: stage tile 0
    i32x4 kreg[3], vreg[2];
#pragma unroll
    for (int i = 0; i < 3; ++i) kreg[i] = *(const i32x4*)(kb_base + kg_[i]);
#pragma unroll
    for (int i = 0; i < 2; ++i) vreg[i] = *(const i32x4*)(vt_base + vg_[i]);
#pragma unroll
    for (int i = 0; i < 3; ++i) *(i32x4*)&Ks[0][kl_[i]] = kreg[i];
#pragma unroll
    for (int i = 0; i < 2; ++i) *(i32x4*)&Vs[0][vl_[i]] = vreg[i];
    __syncthreads();

    int cur = 0;
    for (int kt = 0; kt < 64; ++kt) {
        // issue global loads for tile kt+1 (land under QK^T + PV)
        if (kt < 63) {
#pragma unroll
            for (int i = 0; i < 3; ++i)
                kreg[i] = *(const i32x4*)(kb_base +
                          (size_t)(kt + 1) * 32 * QK_LD + kg_[i]);
#pragma unroll
            for (int i = 0; i < 2; ++i)
                vreg[i] = *(const i32x4*)(vt_base + (kt + 1) * 32 + vg_[i]);
        }

        // S^T = K·Q^T : D rows = k (first operand), cols = q (second operand)
        f32x4 sacc[2][2] = {};
        __builtin_amdgcn_s_setprio(1);
#pragma unroll
        for (int c = 0; c < 6; ++c) {
#pragma unroll
            for (int nk = 0; nk < 2; ++nk) {
                bf16x8 kb = *(const bf16x8*)&Ks[cur][(nk * 16 + l15) * 192 +
                              (((c * 4 + q4) ^ (l15 & 7)) << 3)];
#pragma unroll
                for (int mb = 0; mb < 2; ++mb)
                    sacc[mb][nk] = __builtin_amdgcn_mfma_f32_16x16x32_bf16(
                        kb, qf[mb][c], sacc[mb][nk], 0, 0, 0);
            }
        }
        __builtin_amdgcn_s_setprio(0);

        // exp + in-register P redistribution (replaces Ps LDS round trip).
        // Lane holds S[k = nk*16 + q4*4 + r][q = mb*16 + l15]; PV A-fragment
        // needs P[q = l15][k = q4*8 + j] -- same l15, k moves across q4 groups.
        bf16x8 paf[2];
#pragma unroll
        for (int mb = 0; mb < 2; ++mb) {
            unsigned pk[2][2];
#pragma unroll
            for (int nk = 0; nk < 2; ++nk) {
                float e[4];
#pragma unroll
                for (int r = 0; r < 4; ++r) {
                    e[r] = __expf(fminf(sacc[mb][nk][r] * scale, 50.0f));
                    denom[mb] += e[r];
                }
                pk[nk][0] = packbf(e[0], e[1]);
                pk[nk][1] = packbf(e[2], e[3]);
            }
            unsigned d[4];
#pragma unroll
            for (int p = 0; p < 4; ++p) {
                int sl = (p & 2) ? srcB : srcA;
                unsigned va = (unsigned)__shfl((int)pk[0][p & 1], sl, 64);
                unsigned vb = (unsigned)__shfl((int)pk[1][p & 1], sl, 64);
                d[p] = hiK ? vb : va;
            }
            i32x4 di;
            di[0] = (int)d[0]; di[1] = (int)d[1];
            di[2] = (int)d[2]; di[3] = (int)d[3];
            paf[mb] = __builtin_bit_cast(bf16x8, di);
        }

        // PV: 32 q x 128 d over 32 keys, P from registers
        __builtin_amdgcn_s_setprio(1);
#pragma unroll
        for (int nb = 0; nb < 8; ++nb) {
            bf16x8 vb = *(const bf16x8*)&Vs[cur][(nb * 16 + l15) * 32 +
                          ((q4 ^ (l15 & 3)) << 3)];
#pragma unroll
            for (int mb = 0; mb < 2; ++mb)
                oacc[mb][nb] = __builtin_amdgcn_mfma_f32_16x16x32_bf16(
                    paf[mb], vb, oacc[mb][nb], 0, 0, 0);
        }
        __builtin_amdgcn_s_setprio(0);

        // write tile kt+1 into the other buffer; single barrier per tile
        if (kt < 63) {
#pragma unroll
            for (int i = 0; i < 3; ++i) *(i32x4*)&Ks[cur ^ 1][kl_[i]] = kreg[i];
#pragma unroll
            for (int i = 0; i < 2; ++i) *(i32x4*)&Vs[cur ^ 1][vl_[i]] = vreg[i];
        }
        __syncthreads();
        cur ^= 1;
    }

    // denom: each lane has partials over k in {q4-dependent set}; sum across q4 groups
#pragma unroll
    for (int mb = 0; mb < 2; ++mb) {
        denom[mb] += __shfl_xor(denom[mb], 16, 64);
        denom[mb] += __shfl_xor(denom[mb], 32, 64);
    }

#pragma unroll
    for (int mb = 0; mb < 2; ++mb)
#pragma unroll
        for (int r = 0; r < 4; ++r) {
            float dv = __shfl(denom[mb], q4 * 4 + r, 64);   // lane l15 = q4*4+r holds q
            float inv = 1.0f / dv;
            int row = qt * 128 + w * 32 + mb * 16 + q4 * 4 + r;
#pragma unroll
            for (int nb = 0; nb < 8; ++nb) {
                int col = h * 128 + nb * 16 + l15;
                attnout[(size_t)(b * S_LEN + row) * 2048 + col] =
                    (bf16)(oacc[mb][nb][r] * inv);
            }
        }
}

extern "C" void kernel_launch(void* const* d_in, const int* in_sizes, int n_in,
                              void* d_out, int out_size, void* d_ws, size_t ws_size,
                              hipStream_t stream) {
    const float* x   = (const float*)d_in[0];
    const float* Wd  = (const float*)d_in[1];
    const float* bd  = (const float*)d_in[2];
    const float* Wu  = (const float*)d_in[3];
    const float* bu  = (const float*)d_in[4];
    const float* Wqd = (const float*)d_in[5];
    const float* bqd = (const float*)d_in[6];
    const float* Wqu = (const float*)d_in[7];
    const float* bqu = (const float*)d_in[8];
    const float* Wqr = (const float*)d_in[9];
    const float* bqr = (const float*)d_in[10];
    const float* Wkr = (const float*)d_in[11];
    const float* bkr = (const float*)d_in[12];
    const float* Wo  = (const float*)d_in[13];
    const float* bo  = (const float*)d_in[14];
    float* out = (float*)d_out;

    char* p = (char*)d_ws;
    auto alloc = [&](size_t n) { char* r = p; p += (n + 255) & ~(size_t)255; return r; };
    bf16* xb    = (bf16*)alloc((size_t)4096 * 2048 * 2);
    bf16* W1T   = (bf16*)alloc((size_t)2304 * 2048 * 2);   // [Wd|Wqd|Wkr]^T
    bf16* W2T   = (bf16*)alloc((size_t)3072 * 768 * 2);    // [Wqu|Wqr]^T
    bf16* WuT   = (bf16*)alloc((size_t)2048 * 512 * 2);
    bf16* WoT   = (bf16*)alloc((size_t)2048 * 2048 * 2);
    bf16* xproj = (bf16*)alloc((size_t)4096 * 2304 * 2);   // [kvc|qcmp]
    bf16* qbuf  = (bf16*)alloc((size_t)4096 * 3072 * 2);
    bf16* kbuf  = (bf16*)alloc((size_t)4096 * 3072 * 2);
    bf16* vt    = (bf16*)alloc((size_t)32 * 128 * 2048 * 2);
    bf16* aout  = (bf16*)alloc((size_t)4096 * 2048 * 2);
    float* bcat = (float*)alloc((size_t)5376 * 4);
    float2* tab = (float2*)alloc((size_t)65536 * 8);

    cast_f32_bf16<<<dim3(4096), dim3(256), 0, stream>>>(x, xb);

    TArgs ta;
    ta.s[0] = {Wd,  W1T,                       2048, 512,  0};
    ta.s[1] = {Wqd, W1T + (size_t)512 * 2048,  2048, 768,  256};
    ta.s[2] = {Wkr, W1T + (size_t)1280 * 2048, 2048, 1024, 640};
    ta.s[3] = {Wqu, W2T,                       768,  2048, 1152};
    ta.s[4] = {Wqr, W2T + (size_t)2048 * 768,  768,  1024, 1536};
    ta.s[5] = {Wu,  WuT,                       512,  2048, 1728};
    ta.s[6] = {Wo,  WoT,                       2048, 2048, 1984};
    transpose_all<<<dim3(3008), dim3(256), 0, stream>>>(ta);
    setup_small<<<dim3(277), dim3(256), 0, stream>>>(bd, bqd, bkr, bqu, bqr, bcat, tab);

    // GEMM1: x @ [Wd|Wqd|Wkr] -> xproj cols 0..1279, rope(k_r) -> kbuf
    gemm_bt<<<dim3(18, 32), dim3(256), 0, stream>>>(xb, 2048, W1T, bcat,
                                                    xproj, kbuf, 2304, 2048, 4, tab);
    // fused: kvc @ Wu -> kbuf + vt; qcmp @ [Wqu|Wqr] -> qbuf (+rope)
    gemm_up<<<dim3(40, 32), dim3(256), 0, stream>>>(xproj, WuT, bu, kbuf, vt,
                                                    W2T, bcat + 2304, qbuf, tab);

    attn<<<dim3(32, 16), dim3(256), 0, stream>>>(qbuf, kbuf, vt, aout);

    gemm_bt<<<dim3(16, 32), dim3(256), 0, stream>>>(aout, 2048, WoT, bo,
                                                    out, nullptr, 2048, 2048, 1, tab);
}